// Round 18
// baseline (354.838 us; speedup 1.0000x reference)
//
#include <hip/hip_runtime.h>

#define M_ROWS 200000
#define NROWS  64            // rows per block = lanes per wave
#define NBLK   3125          // 200000 / 64, exact
#define DIM1   320
#define OUTD   416
#define FSTRH  196           // featV row stride (bf16 halfs) = 392 B; 2-dword lane stride -> no conflicts
#define LDS_HALFS (NROWS * FSTRH)   // 12544 halfs = 25088 B -> 4 blocks/CU (thread-limited)

typedef __attribute__((ext_vector_type(4))) float f32x4;
typedef __attribute__((ext_vector_type(2))) float f32x2;

static __device__ __forceinline__ float4 ld4(const float* p) {
    return *reinterpret_cast<const float4*>(p);
}
static __device__ __forceinline__ f32x2 ld2(const float* p) {
    return *reinterpret_cast<const f32x2*>(p);
}
static __device__ __forceinline__ f32x2 pkfma(f32x2 a, f32x2 b, f32x2 c) {
    return __builtin_elementwise_fma(a, b, c);   // llvm.fma.v2f32 -> v_pk_fma_f32
}
static __device__ __forceinline__ unsigned short f2bf(float x) {
    unsigned int u = __float_as_uint(x);
    u = (u + 0x7FFFu + ((u >> 16) & 1u)) >> 16;   // RNE
    return (unsigned short)u;
}
static __device__ __forceinline__ float bflo(unsigned int p) {   // low bf16 -> f32
    return __uint_as_float(p << 16);
}
static __device__ __forceinline__ float bfhi(unsigned int p) {   // high bf16 -> f32
    return __uint_as_float(p & 0xFFFF0000u);
}

// R17 (305us) + bf16 featV: LDS 50176 -> 25088 B. R17 was stall-bound (VALUBusy 52%,
// occ 40% ~= 2-3 blocks/CU by LDS) -- at 3 waves/SIMD the ~200cy s_load weight stream
// and LDS latency can't be hidden. 25088 B -> 4 blocks/CU (2048-thread HW max) =
// 32 waves/CU. x1v precision drops to bf16 (harness budgets bf16: thr 0.29, est +0.03).
// F1 (exact f32 x1s), pass structure, SGPR weight streams, stores: verbatim R17.
__global__ __launch_bounds__(512, 4)
void tp_valu_v18(const float* __restrict__ x1,
                 const float* __restrict__ x2,
                 const float* __restrict__ w000,
                 const float* __restrict__ w011,
                 const float* __restrict__ w101,
                 const float* __restrict__ w110,
                 const float* __restrict__ w112,
                 float* __restrict__ out) {
    __shared__ __align__(16) unsigned short featV[LDS_HALFS];

    constexpr float INV3 = 0.57735026918962576f;   // 1/sqrt(3)
    constexpr float INV6 = 0.40824829046386302f;   // 1/sqrt(6)

    const int t   = threadIdx.x;
    const int row = t & 63;
    const int q   = t >> 6;                        // wave id 0..7
    const int wv  = __builtin_amdgcn_readfirstlane(q);
    const long rbase = (long)blockIdx.x * NROWS;

    const float* x1r = x1 + (rbase + row) * DIM1;
    char* rb = reinterpret_cast<char*>(featV) + row * (FSTRH * 2);

    // per-row x2-derived constants, registers for the whole kernel
    const float4 xr2 = ld4(x2 + (rbase + row) * 4);
    const float s2  = xr2.x;
    const float s2I = s2 * INV3;
    const float vxI = xr2.y * INV3, vyI = xr2.z * INV3, vzI = xr2.w * INV3;
    const float v6x = xr2.y * INV6, v6y = xr2.z * INV6, v6z = xr2.w * INV6;

    // ---- stage featV (bf16) = [v0 halfs 0:64 | v1 64:128 | v2 128:192]; wave q covers u=8q..8q+7 ----
    {
        float qf[24];
        #pragma unroll
        for (int c = 0; c < 6; ++c) {
            float4 v = ld4(x1r + 128 + 24*q + 4*c);
            qf[4*c+0]=v.x; qf[4*c+1]=v.y; qf[4*c+2]=v.z; qf[4*c+3]=v.w;
        }
        #pragma unroll
        for (int s = 0; s < 3; ++s) {
            unsigned int pk[4];
            #pragma unroll
            for (int m = 0; m < 4; ++m) {
                const unsigned int lo = f2bf(qf[3*(2*m)   + s]);
                const unsigned int hi = f2bf(qf[3*(2*m+1) + s]);
                pk[m] = lo | (hi << 16);
            }
            // halfs base s*64 + 8q -> uint index s*32 + 4q (8B-aligned)
            *reinterpret_cast<uint2*>(rb + (s*32 + 4*q)*4)     = make_uint2(pk[0], pk[1]);
            *reinterpret_cast<uint2*>(rb + (s*32 + 4*q)*4 + 8) = make_uint2(pk[2], pk[3]);
        }
    }
    __syncthreads();                               // the kernel's ONLY barrier

    const int c16 = wv * 16, c8w = wv * 8, c4w = wv * 4;

    // ---- F1: ONE x1s pass (global, per-lane row, exact f32) -> accA (w000) + accB (w011) ----
    f32x2 accA[8], accB[4];
    #pragma unroll
    for (int i = 0; i < 8; ++i) accA[i] = (f32x2){0.f, 0.f};
    #pragma unroll
    for (int i = 0; i < 4; ++i) accB[i] = (f32x2){0.f, 0.f};
    {
        const float* wa = w000 + c16;
        const float* wb = w011 + c8w;
        #pragma unroll 2
        for (int kt = 0; kt < 16; ++kt) {          // 8 k per tile
            f32x4 xs0 = *reinterpret_cast<const f32x4*>(x1r + kt*8);
            f32x4 xs1 = *reinterpret_cast<const f32x4*>(x1r + kt*8 + 4);
            #pragma unroll
            for (int j = 0; j < 8; ++j) {
                const float fv = (j < 4) ? xs0[j] : xs1[j-4];
                const f32x2 fvv = {fv, fv};
                const float* wpA = wa + (size_t)(kt*8 + j) * 128;
                const float* wpB = wb + (size_t)(kt*8 + j) * 64;
                #pragma unroll
                for (int c = 0; c < 8; ++c)
                    accA[c] = pkfma(ld2(wpA + 2*c), fvv, accA[c]);
                #pragma unroll
                for (int c = 0; c < 4; ++c)
                    accB[c] = pkfma(ld2(wpB + 2*c), fvv, accB[c]);
            }
        }
    }
    {
        const f32x2 s2v = {s2, s2};
        #pragma unroll
        for (int i = 0; i < 8; ++i) accA[i] *= s2v;   // out0 = s2*A + (d @ w110)
    }

    // expansion macro: stream s of u-tile ut -> 4 uints (8 bf16 values)
    #define LOADPK(P0, P1, S, UT)                                            \
        uint2 P0 = *reinterpret_cast<const uint2*>(rb + ((S)*32 + 4*(UT))*4);\
        uint2 P1 = *reinterpret_cast<const uint2*>(rb + ((S)*32 + 4*(UT))*4 + 8);

    // ---- F2: d pass -> accA += (x1v.v2)*INV3 @ w110 (packed d from bf16 pairs) ----
    {
        const float* wa = w110 + c16;
        const f32x2 vx2 = {vxI, vxI}, vy2 = {vyI, vyI}, vz2 = {vzI, vzI};
        #pragma unroll 2
        for (int ut = 0; ut < 8; ++ut) {
            LOADPK(pa0, pa1, 0, ut)
            LOADPK(pb0, pb1, 1, ut)
            LOADPK(pc0, pc1, 2, ut)
            const unsigned int pa[4] = {pa0.x, pa0.y, pa1.x, pa1.y};
            const unsigned int pb[4] = {pb0.x, pb0.y, pb1.x, pb1.y};
            const unsigned int pc[4] = {pc0.x, pc0.y, pc1.x, pc1.y};
            f32x2 dp[4];
            #pragma unroll
            for (int m = 0; m < 4; ++m) {
                const f32x2 a2 = {bflo(pa[m]), bfhi(pa[m])};
                const f32x2 b2 = {bflo(pb[m]), bfhi(pb[m])};
                const f32x2 c2 = {bflo(pc[m]), bfhi(pc[m])};
                dp[m] = pkfma(c2, vz2, pkfma(b2, vy2, a2 * vx2));
            }
            #pragma unroll
            for (int j = 0; j < 8; ++j) {
                const float fd = dp[j >> 1][j & 1];
                const f32x2 fdd = {fd, fd};
                const float* wp = wa + (size_t)(8*ut + j) * 128;
                #pragma unroll
                for (int c = 0; c < 8; ++c)
                    accA[c] = pkfma(ld2(wp + 2*c), fdd, accA[c]);
            }
        }
    }
    // store out0: 64 B contiguous per lane (8 waves cover cols 0..127)
    {
        float* orow = out + (rbase + row)*OUTD + c16;
        #pragma unroll
        for (int i = 0; i < 4; ++i)
            *reinterpret_cast<float4*>(orow + 4*i) =
                make_float4(accA[2*i][0], accA[2*i][1], accA[2*i+1][0], accA[2*i+1][1]);
    }

    // ---- F3: e pass -> e[3] (w101, 8 cols); combine with held accB ----
    f32x2 e0[4], e1[4], e2[4];
    #pragma unroll
    for (int i = 0; i < 4; ++i) {
        e0[i] = (f32x2){0.f, 0.f}; e1[i] = (f32x2){0.f, 0.f}; e2[i] = (f32x2){0.f, 0.f};
    }
    {
        const float* wb = w101 + c8w;
        #pragma unroll 2
        for (int ut = 0; ut < 8; ++ut) {
            LOADPK(pa0, pa1, 0, ut)
            LOADPK(pb0, pb1, 1, ut)
            LOADPK(pc0, pc1, 2, ut)
            const float a[8] = {bflo(pa0.x), bfhi(pa0.x), bflo(pa0.y), bfhi(pa0.y),
                                bflo(pa1.x), bfhi(pa1.x), bflo(pa1.y), bfhi(pa1.y)};
            const float b[8] = {bflo(pb0.x), bfhi(pb0.x), bflo(pb0.y), bfhi(pb0.y),
                                bflo(pb1.x), bfhi(pb1.x), bflo(pb1.y), bfhi(pb1.y)};
            const float c[8] = {bflo(pc0.x), bfhi(pc0.x), bflo(pc0.y), bfhi(pc0.y),
                                bflo(pc1.x), bfhi(pc1.x), bflo(pc1.y), bfhi(pc1.y)};
            #pragma unroll
            for (int j = 0; j < 8; ++j) {
                const f32x2 faa = {a[j], a[j]}, fbb = {b[j], b[j]}, fcc = {c[j], c[j]};
                const float* wp = wb + (size_t)(8*ut + j) * 64;
                #pragma unroll
                for (int cc = 0; cc < 4; ++cc) {
                    const f32x2 w = ld2(wp + 2*cc);
                    e0[cc] = pkfma(w, faa, e0[cc]);
                    e1[cc] = pkfma(w, fbb, e1[cc]);
                    e2[cc] = pkfma(w, fcc, e2[cc]);
                }
            }
        }
    }
    // out1 epilogue + store: 96 B contiguous per lane at 128 + wv*24
    {
        float vals[24];
        #pragma unroll
        for (int c = 0; c < 8; ++c) {
            const float b   = accB[c >> 1][c & 1];
            const float ev0 = e0[c >> 1][c & 1];
            const float ev1 = e1[c >> 1][c & 1];
            const float ev2 = e2[c >> 1][c & 1];
            vals[3*c+0] = vxI*b + s2I*ev0;
            vals[3*c+1] = vyI*b + s2I*ev1;
            vals[3*c+2] = vzI*b + s2I*ev2;
        }
        float* orow = out + (rbase + row)*OUTD + 128 + wv*24;
        #pragma unroll
        for (int i = 0; i < 6; ++i)
            *reinterpret_cast<float4*>(orow + 4*i) =
                make_float4(vals[4*i], vals[4*i+1], vals[4*i+2], vals[4*i+3]);
    }

    // ---- F4: G pass -> g[3] (w112, 4 cols); cross epilogue ----
    f32x2 g0[2], g1[2], g2[2];
    #pragma unroll
    for (int i = 0; i < 2; ++i) {
        g0[i] = (f32x2){0.f, 0.f}; g1[i] = (f32x2){0.f, 0.f}; g2[i] = (f32x2){0.f, 0.f};
    }
    {
        const float* wb = w112 + c4w;
        #pragma unroll 2
        for (int ut = 0; ut < 8; ++ut) {
            LOADPK(pa0, pa1, 0, ut)
            LOADPK(pb0, pb1, 1, ut)
            LOADPK(pc0, pc1, 2, ut)
            const float a[8] = {bflo(pa0.x), bfhi(pa0.x), bflo(pa0.y), bfhi(pa0.y),
                                bflo(pa1.x), bfhi(pa1.x), bflo(pa1.y), bfhi(pa1.y)};
            const float b[8] = {bflo(pb0.x), bfhi(pb0.x), bflo(pb0.y), bfhi(pb0.y),
                                bflo(pb1.x), bfhi(pb1.x), bflo(pb1.y), bfhi(pb1.y)};
            const float c[8] = {bflo(pc0.x), bfhi(pc0.x), bflo(pc0.y), bfhi(pc0.y),
                                bflo(pc1.x), bfhi(pc1.x), bflo(pc1.y), bfhi(pc1.y)};
            #pragma unroll
            for (int j = 0; j < 8; ++j) {
                const f32x2 faa = {a[j], a[j]}, fbb = {b[j], b[j]}, fcc = {c[j], c[j]};
                const float* wp = wb + (size_t)(8*ut + j) * 32;
                #pragma unroll
                for (int cc = 0; cc < 2; ++cc) {
                    const f32x2 w = ld2(wp + 2*cc);
                    g0[cc] = pkfma(w, faa, g0[cc]);
                    g1[cc] = pkfma(w, fbb, g1[cc]);
                    g2[cc] = pkfma(w, fcc, g2[cc]);
                }
            }
        }
    }
    // out2 epilogue: cross(G, v)*INV6, 48 B contiguous per lane at 320 + wv*12
    {
        float ov[12];
        #pragma unroll
        for (int wl = 0; wl < 4; ++wl) {
            const float G0 = g0[wl >> 1][wl & 1];
            const float G1 = g1[wl >> 1][wl & 1];
            const float G2 = g2[wl >> 1][wl & 1];
            ov[3*wl+0] = G1*v6z - G2*v6y;
            ov[3*wl+1] = G2*v6x - G0*v6z;
            ov[3*wl+2] = G0*v6y - G1*v6x;
        }
        float* orow = out + (rbase + row)*OUTD + 320 + wv*12;
        #pragma unroll
        for (int i = 0; i < 3; ++i)
            *reinterpret_cast<float4*>(orow + 4*i) =
                make_float4(ov[4*i], ov[4*i+1], ov[4*i+2], ov[4*i+3]);
    }
    #undef LOADPK
}

extern "C" void kernel_launch(void* const* d_in, const int* in_sizes, int n_in,
                              void* d_out, int out_size, void* d_ws, size_t ws_size,
                              hipStream_t stream) {
    const float* x1   = (const float*)d_in[0];
    const float* x2   = (const float*)d_in[1];
    const float* w000 = (const float*)d_in[2];
    const float* w011 = (const float*)d_in[3];
    const float* w101 = (const float*)d_in[4];
    const float* w110 = (const float*)d_in[5];
    const float* w112 = (const float*)d_in[6];
    // d_in[7] = w3j111 — folded analytically (cross with v2, scaled 1/sqrt6).
    float* out = (float*)d_out;

    tp_valu_v18<<<dim3(NBLK), dim3(512), 0, stream>>>(
        x1, x2, w000, w011, w101, w110, w112, out);
}

// Round 19
// 305.985 us; speedup vs baseline: 1.1597x; 1.1597x over previous
//
#include <hip/hip_runtime.h>

#define M_ROWS 200000
#define NROWS  64            // rows per block = lanes per wave
#define NBLK   3125          // 200000 / 64, exact
#define DIM1   320
#define OUTD   416
#define FSTR   196           // featV row stride (floats); measured 0 conflicts (R12/R13/R16/R17)
#define LDS_FLOATS (NROWS * FSTR)   // 12544 floats = 50176 B

typedef __attribute__((ext_vector_type(4))) float f32x4;
typedef __attribute__((ext_vector_type(2))) float f32x2;

static __device__ __forceinline__ float4 ld4(const float* p) {
    return *reinterpret_cast<const float4*>(p);
}
static __device__ __forceinline__ f32x2 ld2(const float* p) {
    return *reinterpret_cast<const f32x2*>(p);
}
// llvm.fma.v2f32 -> v_pk_fma_f32 on gfx950 (R17: -12us vs scalarized R16)
static __device__ __forceinline__ f32x2 pkfma(f32x2 a, f32x2 b, f32x2 c) {
    return __builtin_elementwise_fma(a, b, c);
}

// === R17 revert (best: 305.3us). ===
// Structure log: lane=row map -> weight addresses wave-uniform -> SGPR s_load
// streams (VGPR 52); ONE LDS staging (raw x1v, f32) + ONE barrier; x1 read once;
// F1 fuses w000+w011 over the single x1s pass; F2 merges w110 into out0's acc;
// packed v_pk_fma_f32 everywhere. Rejected by measurement: quad-map stores (R7),
// launch_bounds(,3+) reg-squeeze (R8), manual dbuf+unroll1 (R10), F2-4 mega-fusion
// (R14), coalesced x1s LDS staging (R15), bf16 featV for occupancy (R18).
__global__ __launch_bounds__(512, 4)
void tp_valu_v19(const float* __restrict__ x1,
                 const float* __restrict__ x2,
                 const float* __restrict__ w000,
                 const float* __restrict__ w011,
                 const float* __restrict__ w101,
                 const float* __restrict__ w110,
                 const float* __restrict__ w112,
                 float* __restrict__ out) {
    __shared__ __align__(16) float featV[LDS_FLOATS];

    constexpr float INV3 = 0.57735026918962576f;   // 1/sqrt(3)
    constexpr float INV6 = 0.40824829046386302f;   // 1/sqrt(6)

    const int t   = threadIdx.x;
    const int row = t & 63;
    const int q   = t >> 6;                        // wave id 0..7
    const int wv  = __builtin_amdgcn_readfirstlane(q);
    const long rbase = (long)blockIdx.x * NROWS;

    const float* x1r = x1 + (rbase + row) * DIM1;
    float* frS = featV + row * FSTR;

    // per-row x2-derived constants, registers for the whole kernel
    const float4 xr2 = ld4(x2 + (rbase + row) * 4);
    const float s2  = xr2.x;
    const float s2I = s2 * INV3;
    const float vxI = xr2.y * INV3, vyI = xr2.z * INV3, vzI = xr2.w * INV3;
    const float v6x = xr2.y * INV6, v6y = xr2.z * INV6, v6z = xr2.w * INV6;

    // ---- stage featV = [v0 (0:64) | v1 (64:128) | v2 (128:192)]; wave q covers u=8q..8q+7 ----
    {
        float qf[24];
        #pragma unroll
        for (int c = 0; c < 6; ++c) {
            float4 v = ld4(x1r + 128 + 24*q + 4*c);
            qf[4*c+0]=v.x; qf[4*c+1]=v.y; qf[4*c+2]=v.z; qf[4*c+3]=v.w;
        }
        #pragma unroll
        for (int i = 0; i < 8; ++i) {
            const int u = 8*q + i;
            frS[u]       = qf[3*i+0];
            frS[64 + u]  = qf[3*i+1];
            frS[128 + u] = qf[3*i+2];
        }
    }
    __syncthreads();                               // the kernel's ONLY barrier

    const int c16 = wv * 16, c8w = wv * 8, c4w = wv * 4;

    // ---- F1: ONE x1s pass (global, per-lane row) -> accA (w000, 16 cols) + accB (w011, 8 cols) ----
    f32x2 accA[8], accB[4];
    #pragma unroll
    for (int i = 0; i < 8; ++i) accA[i] = (f32x2){0.f, 0.f};
    #pragma unroll
    for (int i = 0; i < 4; ++i) accB[i] = (f32x2){0.f, 0.f};
    {
        const float* wa = w000 + c16;
        const float* wb = w011 + c8w;
        #pragma unroll 2
        for (int kt = 0; kt < 16; ++kt) {          // 8 k per tile
            f32x4 xs0 = *reinterpret_cast<const f32x4*>(x1r + kt*8);
            f32x4 xs1 = *reinterpret_cast<const f32x4*>(x1r + kt*8 + 4);
            #pragma unroll
            for (int j = 0; j < 8; ++j) {
                const float fv = (j < 4) ? xs0[j] : xs1[j-4];
                const f32x2 fvv = {fv, fv};
                const float* wpA = wa + (size_t)(kt*8 + j) * 128;
                const float* wpB = wb + (size_t)(kt*8 + j) * 64;
                #pragma unroll
                for (int c = 0; c < 8; ++c)
                    accA[c] = pkfma(ld2(wpA + 2*c), fvv, accA[c]);
                #pragma unroll
                for (int c = 0; c < 4; ++c)
                    accB[c] = pkfma(ld2(wpB + 2*c), fvv, accB[c]);
            }
        }
    }
    {
        const f32x2 s2v = {s2, s2};
        #pragma unroll
        for (int i = 0; i < 8; ++i) accA[i] *= s2v;   // out0 = s2*A + (d @ w110)
    }

    // ---- F2: d pass (LDS v streams) -> accA += (x1v.v2)*INV3 @ w110 ----
    {
        const float* wa = w110 + c16;
        const f32x2 vx2 = {vxI, vxI}, vy2 = {vyI, vyI}, vz2 = {vzI, vzI};
        #pragma unroll 2
        for (int ut = 0; ut < 8; ++ut) {           // 8 u per tile
            f32x2 dp[4];
            #pragma unroll
            for (int p = 0; p < 4; ++p) {          // packed d: pairs of adjacent u
                f32x2 ap = ld2(frS + 8*ut + 2*p);
                f32x2 bp = ld2(frS + 64 + 8*ut + 2*p);
                f32x2 cp = ld2(frS + 128 + 8*ut + 2*p);
                dp[p] = pkfma(cp, vz2, pkfma(bp, vy2, ap * vx2));
            }
            #pragma unroll
            for (int j = 0; j < 8; ++j) {
                const float fd = dp[j >> 1][j & 1];
                const f32x2 fdd = {fd, fd};
                const float* wp = wa + (size_t)(8*ut + j) * 128;
                #pragma unroll
                for (int c = 0; c < 8; ++c)
                    accA[c] = pkfma(ld2(wp + 2*c), fdd, accA[c]);
            }
        }
    }
    // store out0: 64 B contiguous per lane (8 waves cover cols 0..127)
    {
        float* orow = out + (rbase + row)*OUTD + c16;
        #pragma unroll
        for (int i = 0; i < 4; ++i)
            *reinterpret_cast<float4*>(orow + 4*i) =
                make_float4(accA[2*i][0], accA[2*i][1], accA[2*i+1][0], accA[2*i+1][1]);
    }

    // ---- F3: e pass (LDS v streams) -> e[3] (w101, 8 cols); combine with held accB ----
    f32x2 e0[4], e1[4], e2[4];
    #pragma unroll
    for (int i = 0; i < 4; ++i) {
        e0[i] = (f32x2){0.f, 0.f}; e1[i] = (f32x2){0.f, 0.f}; e2[i] = (f32x2){0.f, 0.f};
    }
    {
        const float* wb = w101 + c8w;
        #pragma unroll 2
        for (int ut = 0; ut < 8; ++ut) {
            f32x4 a0 = *reinterpret_cast<const f32x4*>(frS + 8*ut);
            f32x4 a1 = *reinterpret_cast<const f32x4*>(frS + 8*ut + 4);
            f32x4 b0 = *reinterpret_cast<const f32x4*>(frS + 64 + 8*ut);
            f32x4 b1 = *reinterpret_cast<const f32x4*>(frS + 64 + 8*ut + 4);
            f32x4 c0 = *reinterpret_cast<const f32x4*>(frS + 128 + 8*ut);
            f32x4 c1 = *reinterpret_cast<const f32x4*>(frS + 128 + 8*ut + 4);
            #pragma unroll
            for (int j = 0; j < 8; ++j) {
                const float fa = (j < 4) ? a0[j] : a1[j-4];
                const float fb = (j < 4) ? b0[j] : b1[j-4];
                const float fc = (j < 4) ? c0[j] : c1[j-4];
                const f32x2 faa = {fa, fa}, fbb = {fb, fb}, fcc = {fc, fc};
                const float* wp = wb + (size_t)(8*ut + j) * 64;
                #pragma unroll
                for (int c = 0; c < 4; ++c) {
                    const f32x2 w = ld2(wp + 2*c);
                    e0[c] = pkfma(w, faa, e0[c]);
                    e1[c] = pkfma(w, fbb, e1[c]);
                    e2[c] = pkfma(w, fcc, e2[c]);
                }
            }
        }
    }
    // out1 epilogue + store: 96 B contiguous per lane at 128 + wv*24
    {
        float vals[24];
        #pragma unroll
        for (int c = 0; c < 8; ++c) {
            const float b   = accB[c >> 1][c & 1];
            const float ev0 = e0[c >> 1][c & 1];
            const float ev1 = e1[c >> 1][c & 1];
            const float ev2 = e2[c >> 1][c & 1];
            vals[3*c+0] = vxI*b + s2I*ev0;
            vals[3*c+1] = vyI*b + s2I*ev1;
            vals[3*c+2] = vzI*b + s2I*ev2;
        }
        float* orow = out + (rbase + row)*OUTD + 128 + wv*24;
        #pragma unroll
        for (int i = 0; i < 6; ++i)
            *reinterpret_cast<float4*>(orow + 4*i) =
                make_float4(vals[4*i], vals[4*i+1], vals[4*i+2], vals[4*i+3]);
    }

    // ---- F4: G pass (LDS v streams) -> g[3] (w112, 4 cols); cross epilogue ----
    f32x2 g0[2], g1[2], g2[2];
    #pragma unroll
    for (int i = 0; i < 2; ++i) {
        g0[i] = (f32x2){0.f, 0.f}; g1[i] = (f32x2){0.f, 0.f}; g2[i] = (f32x2){0.f, 0.f};
    }
    {
        const float* wb = w112 + c4w;
        #pragma unroll 2
        for (int ut = 0; ut < 8; ++ut) {
            f32x4 a0 = *reinterpret_cast<const f32x4*>(frS + 8*ut);
            f32x4 a1 = *reinterpret_cast<const f32x4*>(frS + 8*ut + 4);
            f32x4 b0 = *reinterpret_cast<const f32x4*>(frS + 64 + 8*ut);
            f32x4 b1 = *reinterpret_cast<const f32x4*>(frS + 64 + 8*ut + 4);
            f32x4 c0 = *reinterpret_cast<const f32x4*>(frS + 128 + 8*ut);
            f32x4 c1 = *reinterpret_cast<const f32x4*>(frS + 128 + 8*ut + 4);
            #pragma unroll
            for (int j = 0; j < 8; ++j) {
                const float fa = (j < 4) ? a0[j] : a1[j-4];
                const float fb = (j < 4) ? b0[j] : b1[j-4];
                const float fc = (j < 4) ? c0[j] : c1[j-4];
                const f32x2 faa = {fa, fa}, fbb = {fb, fb}, fcc = {fc, fc};
                const float* wp = wb + (size_t)(8*ut + j) * 32;
                #pragma unroll
                for (int c = 0; c < 2; ++c) {
                    const f32x2 w = ld2(wp + 2*c);
                    g0[c] = pkfma(w, faa, g0[c]);
                    g1[c] = pkfma(w, fbb, g1[c]);
                    g2[c] = pkfma(w, fcc, g2[c]);
                }
            }
        }
    }
    // out2 epilogue: cross(G, v)*INV6, 48 B contiguous per lane at 320 + wv*12
    {
        float ov[12];
        #pragma unroll
        for (int wl = 0; wl < 4; ++wl) {
            const float G0 = g0[wl >> 1][wl & 1];
            const float G1 = g1[wl >> 1][wl & 1];
            const float G2 = g2[wl >> 1][wl & 1];
            ov[3*wl+0] = G1*v6z - G2*v6y;
            ov[3*wl+1] = G2*v6x - G0*v6z;
            ov[3*wl+2] = G0*v6y - G1*v6x;
        }
        float* orow = out + (rbase + row)*OUTD + 320 + wv*12;
        #pragma unroll
        for (int i = 0; i < 3; ++i)
            *reinterpret_cast<float4*>(orow + 4*i) =
                make_float4(ov[4*i], ov[4*i+1], ov[4*i+2], ov[4*i+3]);
    }
}

extern "C" void kernel_launch(void* const* d_in, const int* in_sizes, int n_in,
                              void* d_out, int out_size, void* d_ws, size_t ws_size,
                              hipStream_t stream) {
    const float* x1   = (const float*)d_in[0];
    const float* x2   = (const float*)d_in[1];
    const float* w000 = (const float*)d_in[2];
    const float* w011 = (const float*)d_in[3];
    const float* w101 = (const float*)d_in[4];
    const float* w110 = (const float*)d_in[5];
    const float* w112 = (const float*)d_in[6];
    // d_in[7] = w3j111 — folded analytically (cross with v2, scaled 1/sqrt6).
    float* out = (float*)d_out;

    tp_valu_v19<<<dim3(NBLK), dim3(512), 0, stream>>>(
        x1, x2, w000, w011, w101, w110, w112, out);
}

// Round 20
// 224.280 us; speedup vs baseline: 1.5821x; 1.3643x over previous
//
#include <hip/hip_runtime.h>

#define M_ROWS 200000
#define NROWS  64            // rows per block = lanes per wave
#define NBLK   3125          // 200000 / 64, exact
#define DIM1   320
#define OUTD   416
#define FSTR   196           // stage/featV row stride (floats); 0 conflicts measured (R12+)
#define LDS_FLOATS (NROWS * FSTR)   // 12544 floats = 50176 B static (<64KB: R3-R5's >64KB dynamic LDS suspected corrupt)
#define NFRAG  48            // 32 w000-frags + 16 w011-frags, 1024 B each = 49152 B (fits in same buffer)

typedef __attribute__((ext_vector_type(4))) float f32x4;
typedef __attribute__((ext_vector_type(2))) float f32x2;
typedef __attribute__((ext_vector_type(8))) short short8;

static __device__ __forceinline__ float4 ld4(const float* p) {
    return *reinterpret_cast<const float4*>(p);
}
static __device__ __forceinline__ f32x2 ld2(const float* p) {
    return *reinterpret_cast<const f32x2*>(p);
}
static __device__ __forceinline__ f32x2 pkfma(f32x2 a, f32x2 b, f32x2 c) {
    return __builtin_elementwise_fma(a, b, c);   // v_pk_fma_f32
}
static __device__ __forceinline__ unsigned short f2bf(float x) {
    unsigned int u = __float_as_uint(x);
    u = (u + 0x7FFFu + ((u >> 16) & 1u)) >> 16;   // RNE
    return (unsigned short)u;
}

// Hybrid: F1 (x1s@w000, x1s@w011 — 60% of MACs) via bf16 MFMA with STATIC <64KB LDS;
// C-tiles transposed through LDS (FSTR=196) back to lane=row regs; F2/F3/F4 + all
// epilogues/stores verbatim R19 (best f32: 305us). A/B frags use the SAME k-packing
// (k = (lane>>4)*8+j) -> any HW k-permutation cancels; C/D: col=lane&15,
// row=(lane>>4)*4+reg (m89-verified).
__global__ __launch_bounds__(512, 4)
void tp_hyb_v20(const float* __restrict__ x1,
                const float* __restrict__ x2,
                const float* __restrict__ w000,
                const float* __restrict__ w011,
                const float* __restrict__ w101,
                const float* __restrict__ w110,
                const float* __restrict__ w112,
                float* __restrict__ out) {
    __shared__ __align__(16) float lds[LDS_FLOATS];
    char* fragb = reinterpret_cast<char*>(lds);

    constexpr float INV3 = 0.57735026918962576f;   // 1/sqrt(3)
    constexpr float INV6 = 0.40824829046386302f;   // 1/sqrt(6)

    const int t   = threadIdx.x;
    const int row = t & 63;                        // lane = row (64-thread waves)
    const int q   = t >> 6;                        // wave id 0..7
    const int wv  = __builtin_amdgcn_readfirstlane(q);
    const long rbase = (long)blockIdx.x * NROWS;

    const float* x1r = x1 + (rbase + row) * DIM1;
    float* frS = lds + row * FSTR;

    // per-row x2-derived constants
    const float4 xr2 = ld4(x2 + (rbase + row) * 4);
    const float s2  = xr2.x;
    const float s2I = s2 * INV3;
    const float vxI = xr2.y * INV3, vyI = xr2.z * INV3, vzI = xr2.w * INV3;
    const float v6x = xr2.y * INV6, v6y = xr2.z * INV6, v6z = xr2.w * INV6;

    // ---- phase 0: pack B-frags (bf16, raw scale). f<32: w000 [f=nt*4+ks]; else w011 [f=32+nt*4+ks] ----
    #pragma unroll
    for (int it = 0; it < 6; ++it) {
        const int slot = it * 512 + t;             // 0..3071 = 48 frags x 64 lanes
        const int f = slot >> 6;
        const int l = slot & 63;
        const float* src; int ldn, g;
        if (f < 32) { src = w000; ldn = 128; g = f; }
        else        { src = w011; ldn = 64;  g = f - 32; }
        const int nt  = g >> 2, ks = g & 3;
        const int k0  = ks * 32 + (l >> 4) * 8;
        const int col = nt * 16 + (l & 15);
        short8 v;
        #pragma unroll
        for (int j = 0; j < 8; ++j)
            v[j] = (short)f2bf(src[(size_t)(k0 + j) * ldn + col]);
        *reinterpret_cast<short8*>(fragb + (size_t)f * 1024 + l * 16) = v;
    }
    __syncthreads();

    // ---- F1-MFMA: wave -> row-tile rt = wv>>1 (16 rows), col-half h = wv&1 ----
    const int rt = wv >> 1, h = wv & 1;
    f32x4 acc0[4], accB1[2];
    #pragma unroll
    for (int i = 0; i < 4; ++i) acc0[i] = (f32x4){0.f, 0.f, 0.f, 0.f};
    #pragma unroll
    for (int i = 0; i < 2; ++i) accB1[i] = (f32x4){0.f, 0.f, 0.f, 0.f};
    {
        // A-row for this lane: rbase + rt*16 + (lane&15); k-slice (lane>>4)*8
        const float* abase = x1 + (rbase + rt * 16 + (row & 15)) * DIM1 + (row >> 4) * 8;
        #pragma unroll
        for (int ks = 0; ks < 4; ++ks) {
            f32x4 p0 = *reinterpret_cast<const f32x4*>(abase + ks * 32);
            f32x4 p1 = *reinterpret_cast<const f32x4*>(abase + ks * 32 + 4);
            short8 af;
            #pragma unroll
            for (int j = 0; j < 4; ++j) {
                af[j]     = (short)f2bf(p0[j]);
                af[4 + j] = (short)f2bf(p1[j]);
            }
            #pragma unroll
            for (int i = 0; i < 4; ++i) {
                const short8 bf = *reinterpret_cast<const short8*>(
                    fragb + (size_t)((4*h + i) * 4 + ks) * 1024 + row * 16);
                acc0[i] = __builtin_amdgcn_mfma_f32_16x16x32_bf16(af, bf, acc0[i], 0, 0, 0);
            }
            #pragma unroll
            for (int i = 0; i < 2; ++i) {
                const short8 bf = *reinterpret_cast<const short8*>(
                    fragb + (size_t)(32 + (2*h + i) * 4 + ks) * 1024 + row * 16);
                accB1[i] = __builtin_amdgcn_mfma_f32_16x16x32_bf16(af, bf, accB1[i], 0, 0, 0);
            }
        }
    }
    __syncthreads();   // frags fully consumed before stage overwrite

    // ---- C transpose -> LDS stage[row][FSTR]: out0 cols 0..127, out1-b cols 128..191 ----
    // D layout: col = lane&15, row = (lane>>4)*4 + r (m89)
    {
        #pragma unroll
        for (int i = 0; i < 4; ++i) {
            const int colb = (4*h + i) * 16 + (row & 15);
            #pragma unroll
            for (int r = 0; r < 4; ++r)
                lds[(rt * 16 + (row >> 4) * 4 + r) * FSTR + colb] = acc0[i][r];
        }
        #pragma unroll
        for (int i = 0; i < 2; ++i) {
            const int colb = 128 + (2*h + i) * 16 + (row & 15);
            #pragma unroll
            for (int r = 0; r < 4; ++r)
                lds[(rt * 16 + (row >> 4) * 4 + r) * FSTR + colb] = accB1[i][r];
        }
    }
    __syncthreads();

    // ---- read back lane=row into R19's accumulator layout ----
    const int c16 = wv * 16, c8w = wv * 8, c4w = wv * 4;
    f32x2 accA[8], accB[4];
    #pragma unroll
    for (int c = 0; c < 8; ++c) accA[c] = ld2(lds + row * FSTR + c16 + 2*c);
    #pragma unroll
    for (int c = 0; c < 4; ++c) accB[c] = ld2(lds + row * FSTR + 128 + c8w + 2*c);
    {
        const f32x2 s2v = {s2, s2};
        #pragma unroll
        for (int i = 0; i < 8; ++i) accA[i] *= s2v;   // out0 = s2*A + (d @ w110)
    }
    __syncthreads();   // stage reads done before featV overwrite

    // ---- stage featV = [v0 | v1 | v2] (verbatim R19) ----
    {
        float qf[24];
        #pragma unroll
        for (int c = 0; c < 6; ++c) {
            float4 v = ld4(x1r + 128 + 24*q + 4*c);
            qf[4*c+0]=v.x; qf[4*c+1]=v.y; qf[4*c+2]=v.z; qf[4*c+3]=v.w;
        }
        #pragma unroll
        for (int i = 0; i < 8; ++i) {
            const int u = 8*q + i;
            frS[u]       = qf[3*i+0];
            frS[64 + u]  = qf[3*i+1];
            frS[128 + u] = qf[3*i+2];
        }
    }
    __syncthreads();

    // ---- F2: d pass -> accA += (x1v.v2)*INV3 @ w110 (verbatim R19) ----
    {
        const float* wa = w110 + c16;
        const f32x2 vx2 = {vxI, vxI}, vy2 = {vyI, vyI}, vz2 = {vzI, vzI};
        #pragma unroll 2
        for (int ut = 0; ut < 8; ++ut) {
            f32x2 dp[4];
            #pragma unroll
            for (int p = 0; p < 4; ++p) {
                f32x2 ap = ld2(frS + 8*ut + 2*p);
                f32x2 bp = ld2(frS + 64 + 8*ut + 2*p);
                f32x2 cp = ld2(frS + 128 + 8*ut + 2*p);
                dp[p] = pkfma(cp, vz2, pkfma(bp, vy2, ap * vx2));
            }
            #pragma unroll
            for (int j = 0; j < 8; ++j) {
                const float fd = dp[j >> 1][j & 1];
                const f32x2 fdd = {fd, fd};
                const float* wp = wa + (size_t)(8*ut + j) * 128;
                #pragma unroll
                for (int c = 0; c < 8; ++c)
                    accA[c] = pkfma(ld2(wp + 2*c), fdd, accA[c]);
            }
        }
    }
    // store out0: 64 B contiguous per lane
    {
        float* orow = out + (rbase + row)*OUTD + c16;
        #pragma unroll
        for (int i = 0; i < 4; ++i)
            *reinterpret_cast<float4*>(orow + 4*i) =
                make_float4(accA[2*i][0], accA[2*i][1], accA[2*i+1][0], accA[2*i+1][1]);
    }

    // ---- F3: e pass -> e[3] (w101); combine with accB (verbatim R19) ----
    f32x2 e0[4], e1[4], e2[4];
    #pragma unroll
    for (int i = 0; i < 4; ++i) {
        e0[i] = (f32x2){0.f, 0.f}; e1[i] = (f32x2){0.f, 0.f}; e2[i] = (f32x2){0.f, 0.f};
    }
    {
        const float* wb = w101 + c8w;
        #pragma unroll 2
        for (int ut = 0; ut < 8; ++ut) {
            f32x4 a0 = *reinterpret_cast<const f32x4*>(frS + 8*ut);
            f32x4 a1 = *reinterpret_cast<const f32x4*>(frS + 8*ut + 4);
            f32x4 b0 = *reinterpret_cast<const f32x4*>(frS + 64 + 8*ut);
            f32x4 b1 = *reinterpret_cast<const f32x4*>(frS + 64 + 8*ut + 4);
            f32x4 c0 = *reinterpret_cast<const f32x4*>(frS + 128 + 8*ut);
            f32x4 c1 = *reinterpret_cast<const f32x4*>(frS + 128 + 8*ut + 4);
            #pragma unroll
            for (int j = 0; j < 8; ++j) {
                const float fa = (j < 4) ? a0[j] : a1[j-4];
                const float fb = (j < 4) ? b0[j] : b1[j-4];
                const float fc = (j < 4) ? c0[j] : c1[j-4];
                const f32x2 faa = {fa, fa}, fbb = {fb, fb}, fcc = {fc, fc};
                const float* wp = wb + (size_t)(8*ut + j) * 64;
                #pragma unroll
                for (int c = 0; c < 4; ++c) {
                    const f32x2 w = ld2(wp + 2*c);
                    e0[c] = pkfma(w, faa, e0[c]);
                    e1[c] = pkfma(w, fbb, e1[c]);
                    e2[c] = pkfma(w, fcc, e2[c]);
                }
            }
        }
    }
    // out1 epilogue + store
    {
        float vals[24];
        #pragma unroll
        for (int c = 0; c < 8; ++c) {
            const float b   = accB[c >> 1][c & 1];
            const float ev0 = e0[c >> 1][c & 1];
            const float ev1 = e1[c >> 1][c & 1];
            const float ev2 = e2[c >> 1][c & 1];
            vals[3*c+0] = vxI*b + s2I*ev0;
            vals[3*c+1] = vyI*b + s2I*ev1;
            vals[3*c+2] = vzI*b + s2I*ev2;
        }
        float* orow = out + (rbase + row)*OUTD + 128 + wv*24;
        #pragma unroll
        for (int i = 0; i < 6; ++i)
            *reinterpret_cast<float4*>(orow + 4*i) =
                make_float4(vals[4*i], vals[4*i+1], vals[4*i+2], vals[4*i+3]);
    }

    // ---- F4: G pass -> g[3] (w112); cross epilogue (verbatim R19) ----
    f32x2 g0[2], g1[2], g2[2];
    #pragma unroll
    for (int i = 0; i < 2; ++i) {
        g0[i] = (f32x2){0.f, 0.f}; g1[i] = (f32x2){0.f, 0.f}; g2[i] = (f32x2){0.f, 0.f};
    }
    {
        const float* wb = w112 + c4w;
        #pragma unroll 2
        for (int ut = 0; ut < 8; ++ut) {
            f32x4 a0 = *reinterpret_cast<const f32x4*>(frS + 8*ut);
            f32x4 a1 = *reinterpret_cast<const f32x4*>(frS + 8*ut + 4);
            f32x4 b0 = *reinterpret_cast<const f32x4*>(frS + 64 + 8*ut);
            f32x4 b1 = *reinterpret_cast<const f32x4*>(frS + 64 + 8*ut + 4);
            f32x4 c0 = *reinterpret_cast<const f32x4*>(frS + 128 + 8*ut);
            f32x4 c1 = *reinterpret_cast<const f32x4*>(frS + 128 + 8*ut + 4);
            #pragma unroll
            for (int j = 0; j < 8; ++j) {
                const float fa = (j < 4) ? a0[j] : a1[j-4];
                const float fb = (j < 4) ? b0[j] : b1[j-4];
                const float fc = (j < 4) ? c0[j] : c1[j-4];
                const f32x2 faa = {fa, fa}, fbb = {fb, fb}, fcc = {fc, fc};
                const float* wp = wb + (size_t)(8*ut + j) * 32;
                #pragma unroll
                for (int c = 0; c < 2; ++c) {
                    const f32x2 w = ld2(wp + 2*c);
                    g0[c] = pkfma(w, faa, g0[c]);
                    g1[c] = pkfma(w, fbb, g1[c]);
                    g2[c] = pkfma(w, fcc, g2[c]);
                }
            }
        }
    }
    // out2 epilogue: cross(G, v)*INV6
    {
        float ov[12];
        #pragma unroll
        for (int wl = 0; wl < 4; ++wl) {
            const float G0 = g0[wl >> 1][wl & 1];
            const float G1 = g1[wl >> 1][wl & 1];
            const float G2 = g2[wl >> 1][wl & 1];
            ov[3*wl+0] = G1*v6z - G2*v6y;
            ov[3*wl+1] = G2*v6x - G0*v6z;
            ov[3*wl+2] = G0*v6y - G1*v6x;
        }
        float* orow = out + (rbase + row)*OUTD + 320 + wv*12;
        #pragma unroll
        for (int i = 0; i < 3; ++i)
            *reinterpret_cast<float4*>(orow + 4*i) =
                make_float4(ov[4*i], ov[4*i+1], ov[4*i+2], ov[4*i+3]);
    }
}

extern "C" void kernel_launch(void* const* d_in, const int* in_sizes, int n_in,
                              void* d_out, int out_size, void* d_ws, size_t ws_size,
                              hipStream_t stream) {
    const float* x1   = (const float*)d_in[0];
    const float* x2   = (const float*)d_in[1];
    const float* w000 = (const float*)d_in[2];
    const float* w011 = (const float*)d_in[3];
    const float* w101 = (const float*)d_in[4];
    const float* w110 = (const float*)d_in[5];
    const float* w112 = (const float*)d_in[6];
    // d_in[7] = w3j111 — folded analytically (cross with v2, scaled 1/sqrt6).
    float* out = (float*)d_out;

    tp_hyb_v20<<<dim3(NBLK), dim3(512), 0, stream>>>(
        x1, x2, w000, w011, w101, w110, w112, out);
}